// Round 8
// baseline (143.467 us; speedup 1.0000x reference)
//
#include <hip/hip_runtime.h>
#include <hip/hip_bf16.h>

// dist[b,c] = ||x_b||^2 + ||p_c||^2 - 2 x_b . p_c
// B=16384, D=512, C=1000. Single fused kernel: stages fp32 -> bf16 in
// registers (computing row norms on the fly), MFMA cross-term, fused epilogue.

#define B_ROWS 16384
#define D_K    512
#define C_COLS 1000

#define BM 256
#define BN 256
#define BK 32
#define NTL (D_K / BK)  // 16 K-tiles

typedef __attribute__((ext_vector_type(8))) short short8;
typedef __attribute__((ext_vector_type(4))) float f32x4;

__device__ __forceinline__ f32x4 MFMA(short8 a, short8 b, f32x4 c) {
  return __builtin_amdgcn_mfma_f32_16x16x32_bf16(a, b, c, 0, 0, 0);
}

// 256x256 tile, BK=32, 8 waves (2M x 4N, 128x64/wave), 16x16x32 MFMA.
// Reg-staged fused prep: thread t<256 owns A-row t (x), t>=256 owns B-row
// t-256 (protomat, clamped to row 999 -- cols >= 1000 are never stored, so
// clamped data is harmless). Per tile: 8x float4 loads -> cvt_pk bf16 ->
// 4x ds_write_b128 into the chunk-permuted LDS layout (round-5-verified
// conflict-free for reads; write side uniform 8 dwords/bank = b128 floor).
// Row norms accumulate per-thread in fp32 (thread owns the full row) and
// land in a 2 KiB LDS array for the epilogue -- no separate prep kernel.
//
// Schedule (T14 split, 2 LDS bufs, one barrier per tile):
//   iter t (even): GLOAD(RA, t+2); COMPUTE(t, buf0); CVTW(RB -> buf1);
//                  sync; GLOAD(RB, t+3); COMPUTE(t+1, buf1);
//                  CVTW(RA -> buf0); sync
// WAR: CVTW(->buf1) vs COMPUTE(t-1) readers of buf1: separated by the
// previous iteration's trailing sync. CVTW(->buf0) vs COMPUTE(t) readers
// of buf0: separated by the mid sync. RAW: every CVTW is followed by a
// sync before the COMPUTE that reads it. Register loads get compiler-
// inserted counted vmcnt (reg-staging is compiler-friendly).
//
// LDS chunk layout per region (A at 0, B at +8192 ush, per 16384-ush buf):
// fragment (row, ks) at chunk row*4 + ((ks + (row>>1)) & 3).
__global__ __launch_bounds__(512, 1) void fused_kernel(
    const float* __restrict__ x, const float* __restrict__ p,
    float* __restrict__ out) {
  __shared__ __align__(16) unsigned short L[2 * 16384];  // 64 KiB
  __shared__ float SQ[512];  // [0,256): ||x_row||^2, [256,512): ||p_col||^2

  const int tid  = threadIdx.x;
  const int lane = tid & 63;
  const int wave = tid >> 6;
  const int wm   = wave >> 2;  // 0..1
  const int wn   = wave & 3;   // 0..3

  // XCD swizzle: XCD k gets bm in [k*8, k*8+8), all 4 bn.
  const int bid = blockIdx.x;
  const int tt  = (bid & 7) * 32 + (bid >> 3);
  const int bm  = tt >> 2;  // 0..63
  const int bn  = tt & 3;   // 0..3

  // Staging role: one row per thread.
  const int rloc = tid & 255;
  const float* gsrc;
  if (tid < 256) {
    gsrc = x + (size_t)(bm * BM + rloc) * D_K;
  } else {
    int prow = bn * BN + rloc;
    if (prow > C_COLS - 1) prow = C_COLS - 1;
    gsrc = p + (size_t)prow * D_K;
  }
  unsigned short* lreg = L + (tid < 256 ? 0 : 8192);
  const int rsh = (rloc >> 1) & 3;

  float ssq = 0.f;
  float4 RA[8], RB[8];

  auto GLOAD = [&](float4* R, int T) {
    const float4* s = reinterpret_cast<const float4*>(gsrc + T * BK);
#pragma unroll
    for (int j = 0; j < 8; ++j) R[j] = s[j];
  };

  auto CVTW = [&](const float4* R, int BUF) {
    __hip_bfloat162 h[16];
#pragma unroll
    for (int j = 0; j < 8; ++j) {
      ssq += R[j].x * R[j].x + R[j].y * R[j].y + R[j].z * R[j].z +
             R[j].w * R[j].w;
      h[2 * j]     = __float22bfloat162_rn(float2{R[j].x, R[j].y});
      h[2 * j + 1] = __float22bfloat162_rn(float2{R[j].z, R[j].w});
    }
    const uint4* hu = reinterpret_cast<const uint4*>(h);
    unsigned short* base = lreg + BUF * 16384;
#pragma unroll
    for (int ks = 0; ks < 4; ++ks) {
      const int chunk = rloc * 4 + ((ks + rsh) & 3);
      *reinterpret_cast<uint4*>(base + chunk * 8) = hu[ks];
    }
  };

  f32x4 acc[8][4];
#pragma unroll
  for (int m = 0; m < 8; ++m)
#pragma unroll
    for (int n = 0; n < 4; ++n) acc[m][n] = (f32x4){0.f, 0.f, 0.f, 0.f};

  // ds_read bases (ushort units); pos-permuted, round-5-verified.
  const int l15  = lane & 15;
  const int posL = (((lane >> 4) + (l15 >> 1)) & 3);
  const int rdA  = (wm * 128 + l15) * 32 + posL * 8;
  const int rdB  = 8192 + (wn * 64 + l15) * 32 + posL * 8;

  auto COMPUTE = [&](int BUF) {
    const unsigned short* Ab = &L[BUF * 16384] + rdA;
    const unsigned short* Bb = &L[BUF * 16384] + rdB;
    short8 bfr[4];
#pragma unroll
    for (int n = 0; n < 4; ++n)
      bfr[n] = *reinterpret_cast<const short8*>(Bb + n * 512);
    __builtin_amdgcn_s_setprio(1);
#pragma unroll
    for (int m = 0; m < 8; ++m) {
      short8 af = *reinterpret_cast<const short8*>(Ab + m * 512);
#pragma unroll
      for (int n = 0; n < 4; ++n) acc[m][n] = MFMA(af, bfr[n], acc[m][n]);
    }
    __builtin_amdgcn_s_setprio(0);
  };

  // Prologue: tiles 0,1 into regs; tile 0 into buf0.
  GLOAD(RA, 0);
  GLOAD(RB, 1);
  CVTW(RA, 0);
  __syncthreads();

#pragma unroll 1
  for (int t = 0; t < NTL; t += 2) {
    if (t + 2 < NTL) GLOAD(RA, t + 2);
    COMPUTE(0);        // tile t
    CVTW(RB, 1);       // tile t+1 -> buf1
    __syncthreads();
    if (t + 3 < NTL) GLOAD(RB, t + 3);
    COMPUTE(1);        // tile t+1
    if (t + 2 < NTL) CVTW(RA, 0);  // tile t+2 -> buf0
    __syncthreads();
  }

  // Row norms -> LDS (thread owns its full row's sum).
  SQ[tid] = ssq;
  __syncthreads();

  // Epilogue: out[b][c] = xsq[b] + psq[c] - 2*cross
  const int col_l = wn * 64 + l15;
  float pc[4];
#pragma unroll
  for (int n = 0; n < 4; ++n) pc[n] = SQ[256 + col_l + n * 16];

  const int row_l0 = wm * 128 + ((lane >> 4) << 2);
  const int gcol0  = bn * BN + col_l;
#pragma unroll
  for (int m = 0; m < 8; ++m) {
#pragma unroll
    for (int r = 0; r < 4; ++r) {
      const int row_l = row_l0 + m * 16 + r;
      const float xs  = SQ[row_l];
      const size_t gr = (size_t)(bm * BM + row_l) * C_COLS;
#pragma unroll
      for (int n = 0; n < 4; ++n) {
        const int c = gcol0 + n * 16;
        if (c < C_COLS) out[gr + c] = xs + pc[n] - 2.0f * acc[m][n][r];
      }
    }
  }
}

extern "C" void kernel_launch(void* const* d_in, const int* in_sizes, int n_in,
                              void* d_out, int out_size, void* d_ws, size_t ws_size,
                              hipStream_t stream) {
  const float* x = (const float*)d_in[0];
  const float* p = (const float*)d_in[1];
  float* out = (float*)d_out;

  // Single fused kernel: 256 blocks (64 bm x 4 bn), XCD-swizzled, 512 threads.
  fused_kernel<<<256, 512, 0, stream>>>(x, p, out);
}

// Round 9
// 111.145 us; speedup vs baseline: 1.2908x; 1.2908x over previous
//
#include <hip/hip_runtime.h>
#include <hip/hip_bf16.h>

// dist[b,c] = ||x_b||^2 + ||p_c||^2 - 2 x_b . p_c
// B=16384, D=512, C=1000 (padded to 1024 in workspace)

#define B_ROWS 16384
#define D_K    512
#define C_COLS 1000
#define C_PAD  1024

#define BM 256
#define BN 128
#define BK 32
#define NK (D_K / BK)   // 16
#define NBUF 3          // 3-deep LDS pipeline, stage 2 K-tiles ahead
#define ABUF_SH 8192    // A ushorts per buffer (256 rows x 32 k)
#define TILE_SH 12288   // ushorts per buffer (A 8192 + B 4096) = 24 KiB

typedef __attribute__((ext_vector_type(8))) short short8;
typedef __attribute__((ext_vector_type(4))) float f32x4;

// fp32 -> bf16 round-to-nearest-even
__device__ __forceinline__ unsigned short f2bf(float f) {
  unsigned u = __float_as_uint(f);
  u += 0x7fffu + ((u >> 16) & 1u);
  return (unsigned short)(u >> 16);
}

// 16-byte async global->LDS copy (lane-contiguous LDS destination)
__device__ __forceinline__ void gload16(const void* g, void* l) {
  __builtin_amdgcn_global_load_lds(
      (const __attribute__((address_space(1))) unsigned int*)g,
      (__attribute__((address_space(3))) unsigned int*)l, 16, 0, 0);
}

__device__ __forceinline__ f32x4 MFMA(short8 a, short8 b, f32x4 c) {
  return __builtin_amdgcn_mfma_f32_16x16x32_bf16(a, b, c, 0, 0, 0);
}

// One wave per row: cast row to bf16 + fp32 sum of squares.
// Rows [0, B_ROWS) -> x;  rows [B_ROWS, B_ROWS + C_PAD) -> protomat
// (zero-padded past C_COLS).
__global__ __launch_bounds__(256) void prep_kernel(
    const float* __restrict__ x, const float* __restrict__ p,
    unsigned short* __restrict__ xb, unsigned short* __restrict__ pb,
    float* __restrict__ xsq, float* __restrict__ psq) {
  const int wave = threadIdx.x >> 6;
  const int lane = threadIdx.x & 63;
  const int row  = blockIdx.x * 4 + wave;
  const bool isx = row < B_ROWS;
  const int r2   = isx ? row : row - B_ROWS;

  float v[8];
  if (isx) {
    const float4* s = reinterpret_cast<const float4*>(x + (size_t)r2 * D_K + lane * 8);
    float4 a = s[0], b = s[1];
    v[0] = a.x; v[1] = a.y; v[2] = a.z; v[3] = a.w;
    v[4] = b.x; v[5] = b.y; v[6] = b.z; v[7] = b.w;
  } else if (r2 < C_COLS) {
    const float4* s = reinterpret_cast<const float4*>(p + (size_t)r2 * D_K + lane * 8);
    float4 a = s[0], b = s[1];
    v[0] = a.x; v[1] = a.y; v[2] = a.z; v[3] = a.w;
    v[4] = b.x; v[5] = b.y; v[6] = b.z; v[7] = b.w;
  } else {
#pragma unroll
    for (int j = 0; j < 8; ++j) v[j] = 0.0f;
  }

  float ss = 0.0f;
  unsigned short u[8];
#pragma unroll
  for (int j = 0; j < 8; ++j) { ss += v[j] * v[j]; u[j] = f2bf(v[j]); }

  uint4 pk;
  pk.x = (unsigned)u[0] | ((unsigned)u[1] << 16);
  pk.y = (unsigned)u[2] | ((unsigned)u[3] << 16);
  pk.z = (unsigned)u[4] | ((unsigned)u[5] << 16);
  pk.w = (unsigned)u[6] | ((unsigned)u[7] << 16);
  unsigned short* dst = (isx ? xb : pb) + (size_t)r2 * D_K + lane * 8;
  *reinterpret_cast<uint4*>(dst) = pk;

#pragma unroll
  for (int off = 32; off > 0; off >>= 1) ss += __shfl_down(ss, off);
  if (lane == 0) (isx ? xsq : psq)[r2] = ss;
}

// 256x128 tile, BK=32, 8 waves (4M x 2N, 64x64/wave, acc[4][4]), 3-deep
// LDS pipeline with counted vmcnt (stage 2 ahead, never drain mid-loop),
// chunk-permuted conflict-free LDS, XCD swizzle, setprio around MFMA,
// fused distance epilogue. LDS = 3 x 24 KiB = 72 KiB -> 2 blocks/CU
// (the round-5 256x256 version was 128 KiB -> 1 block/CU; the second
// resident block is what overlaps prologue/epilogue/store-tail).
//
// LDS chunk layout per region: fragment (row, kslot) at chunk
// row*4 + ((kslot + (row>>1)) & 3)  (round-5-verified conflict-free).
//
// vmcnt ledger (3 loads/stage, in-order retirement): at iter t's wait
// point outstanding <= 6 {STAGE(t), STAGE(t+1)}; vmcnt(3) -> STAGE(t)
// landed, STAGE(t+1) in flight; then STAGE(t+2) issued -> <= 6 again.
// Tail: t=14 vmcnt(3) {15 in flight}, t=15 vmcnt(0).
// WAR: STAGE(t+2) writes buf[(t+2)%3] = buf[(t-1)%3]; its readers
// (COMPUTE(t-1)) consumed all ds_reads (MFMAs issued) before iter t's
// barrier -> safe. K-loop fully unrolled so %3 indices are compile-time.
__global__ __launch_bounds__(512, 4) void gemm_kernel(
    const unsigned short* __restrict__ xb, const unsigned short* __restrict__ pb,
    const float* __restrict__ xsq, const float* __restrict__ psq,
    float* __restrict__ out) {
  __shared__ __align__(16) unsigned short L[NBUF * TILE_SH];  // 72 KiB

  const int tid  = threadIdx.x;
  const int lane = tid & 63;
  const int wave = tid >> 6;
  const int wm   = wave >> 1;  // 0..3 (M)
  const int wn   = wave & 1;   // 0..1 (N)

  // XCD swizzle: 512 blocks; XCD x gets bm in [x*8, x*8+8), all 8 bn.
  const int bid = blockIdx.x;
  const int tt  = (bid & 7) * 64 + (bid >> 3);
  const int bm  = tt >> 3;  // 0..63
  const int bn  = tt & 7;   // 0..7

  // Staging: A chunks tid, tid+512 (1024 x 16B); B chunk tid (512 x 16B).
  const int rA0 = tid >> 2, rA1 = rA0 + 128, rB = tid >> 2;
  const int ksA0 = ((tid & 3) - (rA0 >> 1)) & 3;
  const int ksA1 = (((tid + 512) & 3) - (rA1 >> 1)) & 3;
  const int ksB  = ((tid & 3) - (rB >> 1)) & 3;
  const unsigned short* gA0 = xb + ((size_t)bm * BM + rA0) * D_K + ksA0 * 8;
  const unsigned short* gA1 = xb + ((size_t)bm * BM + rA1) * D_K + ksA1 * 8;
  const unsigned short* gB  = pb + ((size_t)bn * BN + rB) * D_K + ksB * 8;
  unsigned short* lA0 = &L[tid * 8];
  unsigned short* lA1 = &L[(tid + 512) * 8];
  unsigned short* lB  = &L[ABUF_SH + tid * 8];

  f32x4 acc[4][4];
#pragma unroll
  for (int m = 0; m < 4; ++m)
#pragma unroll
    for (int n = 0; n < 4; ++n) acc[m][n] = (f32x4){0.f, 0.f, 0.f, 0.f};

  // ds_read bases (ushort units); pos-permuted, conflict-free.
  const int l15  = lane & 15;
  const int posL = (((lane >> 4) + (l15 >> 1)) & 3);
  const int rdA  = (wm * 64 + l15) * 32 + posL * 8;
  const int rdB  = ABUF_SH + (wn * 64 + l15) * 32 + posL * 8;

#define STAGE(T, BUF)                                     \
  do {                                                    \
    const int ko = (T)*BK;                                \
    const int bo = (BUF)*TILE_SH;                         \
    gload16(gA0 + ko, lA0 + bo);                          \
    gload16(gA1 + ko, lA1 + bo);                          \
    gload16(gB + ko, lB + bo);                            \
  } while (0)

#define COMPUTE(BUF)                                                          \
  do {                                                                        \
    const unsigned short* Ab = &L[(BUF)*TILE_SH] + rdA;                       \
    const unsigned short* Bb = &L[(BUF)*TILE_SH] + rdB;                       \
    short8 bfr[4];                                                            \
    _Pragma("unroll") for (int n = 0; n < 4; ++n)                             \
        bfr[n] = *reinterpret_cast<const short8*>(Bb + n * 512);              \
    __builtin_amdgcn_s_setprio(1);                                            \
    _Pragma("unroll") for (int m = 0; m < 4; ++m) {                           \
      short8 af = *reinterpret_cast<const short8*>(Ab + m * 512);             \
      _Pragma("unroll") for (int n = 0; n < 4; ++n)                           \
          acc[m][n] = MFMA(af, bfr[n], acc[m][n]);                            \
    }                                                                         \
    __builtin_amdgcn_s_setprio(0);                                            \
  } while (0)

  STAGE(0, 0);
  STAGE(1, 1);

#pragma unroll
  for (int t = 0; t < NK - 2; ++t) {  // fully unrolled: %3 is compile-time
    asm volatile("s_waitcnt vmcnt(3)" ::: "memory");  // tile t landed
    __builtin_amdgcn_s_barrier();
    STAGE(t + 2, (t + 2) % 3);
    COMPUTE(t % 3);
  }
  asm volatile("s_waitcnt vmcnt(3)" ::: "memory");  // tile 14 landed
  __builtin_amdgcn_s_barrier();
  COMPUTE(14 % 3);
  asm volatile("s_waitcnt vmcnt(0)" ::: "memory");  // tile 15 landed
  __builtin_amdgcn_s_barrier();
  COMPUTE(15 % 3);

#undef STAGE
#undef COMPUTE

  // Epilogue: out[b][c] = xsq[b] + psq[c] - 2*cross
  const int colb = bn * BN + wn * 64 + l15;
  float pc[4];
#pragma unroll
  for (int n = 0; n < 4; ++n) pc[n] = psq[colb + n * 16];  // C_PAD: in bounds

  const int rowb = bm * BM + wm * 64 + ((lane >> 4) << 2);
#pragma unroll
  for (int m = 0; m < 4; ++m) {
#pragma unroll
    for (int r = 0; r < 4; ++r) {
      const int row = rowb + m * 16 + r;
      const float xs = xsq[row];
#pragma unroll
      for (int n = 0; n < 4; ++n) {
        const int c = colb + n * 16;
        if (c < C_COLS)
          out[(size_t)row * C_COLS + c] = xs + pc[n] - 2.0f * acc[m][n][r];
      }
    }
  }
}

extern "C" void kernel_launch(void* const* d_in, const int* in_sizes, int n_in,
                              void* d_out, int out_size, void* d_ws, size_t ws_size,
                              hipStream_t stream) {
  const float* x = (const float*)d_in[0];
  const float* p = (const float*)d_in[1];
  float* out = (float*)d_out;

  char* ws = (char*)d_ws;
  unsigned short* xb  = (unsigned short*)ws;                        // 16 MiB
  unsigned short* pb  = (unsigned short*)(ws + 16777216);           // 1 MiB
  float* xsq          = (float*)(ws + 16777216 + 1048576);          // 64 KiB
  float* psq          = (float*)(ws + 16777216 + 1048576 + 65536);  // 4 KiB

  // Prep: one wave per row, (16384 + 1024) rows / 4 waves per block
  prep_kernel<<<(B_ROWS + C_PAD) / 4, 256, 0, stream>>>(x, p, xb, pb, xsq, psq);

  // GEMM: 512 blocks (64 bm x 8 bn), XCD-swizzled, 512 threads, 2 blocks/CU
  gemm_kernel<<<512, 512, 0, stream>>>(xb, pb, xsq, psq, out);
}